// Round 8
// baseline (1788.794 us; speedup 1.0000x reference)
//
#include <hip/hip_runtime.h>
#include <hip/hip_bf16.h>

#define BB 256   // batch
#define TT 512   // time
#define HH 256   // hidden
#define EE 128   // embed
#define KK 15    // tags
#define NGRP 16  // batch groups per direction
#define GB   16  // batch rows per group

typedef __attribute__((ext_vector_type(8))) short short8;
typedef __attribute__((ext_vector_type(4))) float floatx4;
typedef __attribute__((ext_vector_type(4))) unsigned int uint4v;

__device__ __forceinline__ float fsig(float x) { return 1.0f / (1.0f + __expf(-x)); }
__device__ __forceinline__ float ftanh(float x) {
    float e = __expf(2.0f * x);
    return 1.0f - 2.0f / (e + 1.0f);
}
__device__ __forceinline__ unsigned short f2b(float f) {
    __hip_bfloat16 h = __float2bfloat16(f);
    return *reinterpret_cast<unsigned short*>(&h);
}

// ---------------- fused prep: transpose ids/labels + build gate tables ----------------
__global__ void prep_fused(const int* __restrict__ cids, const int* __restrict__ labels,
                           int* __restrict__ cidsT, int* __restrict__ labelsT,
                           const float* __restrict__ embed,
                           const float* __restrict__ WihF, const float* __restrict__ bF,
                           const float* __restrict__ WihB, const float* __restrict__ bB,
                           float* __restrict__ tableF, float* __restrict__ tableB) {
    const int bidx = blockIdx.x;
    const int tid = threadIdx.x;
    if (bidx < 1024) {
        int idx = bidx * 256 + tid;          // 0..262143
        int which = idx >> 17;
        int r = idx & 131071;
        int b = r >> 9, t = r & 511;
        if (which == 0) cidsT[t * BB + b] = cids[b * TT + t];
        else            labelsT[t * BB + b] = labels[b * TT + t];
    } else {
        int idx = (bidx - 1024) * 256 + tid; // 0..262143
        int d = idx >> 17;
        int r = idx & 131071;
        int v = r >> 10, j = r & 1023;
        const float* Wih = d ? WihB : WihF;
        const float* bias = d ? bB : bF;
        float s = bias[j];
        const float* em = embed + v * EE;
        const float* wr = Wih + j * EE;
#pragma unroll 8
        for (int e = 0; e < EE; ++e) s += em[e] * wr[e];
        (d ? tableB : tableF)[v * 1024 + j] = s;
    }
}

// ---------------- BiLSTM: fan-in 2, parity-double-buffered tag-in-data exchange ----------------
// 64 blocks x 512 threads: bid = jb*32 + gi; gi = dir*16 + g; jb in 0..1 owns
// h-cols [jb*128, jb*128+128). Wave wv (0..7) owns cols jb*128 + wv*16 + (lane&15), 4 gates.
// hws: u32 words [parity][gi][col(256)][b(16)], word = (tag<<16) | bf16(h).
// h_s -> slot s&1 with tag s+1; consumer at step s polls slot (s+1)&1 for tag s.
// Parity buffering makes overwrite provably ordered after the partner's read (mutual dep).
// Own half goes straight to LDS; only the partner's 8 KB crosses the Infinity Fabric.
__global__ void __launch_bounds__(512)
bilstm(const float* __restrict__ tableF, const float* __restrict__ tableB,
       const float* __restrict__ WhhF, const float* __restrict__ WhhB,
       const float* __restrict__ fcW,
       const int* __restrict__ cidsT,
       unsigned* __restrict__ hws,
       float* __restrict__ emF, float* __restrict__ emB) {
    const int bid = blockIdx.x;
    const int gi  = bid & 31;
    const int jb  = bid >> 5;          // 0..1
    const int dir = gi >> 4;
    const int g   = gi & 15;
    const int tid = threadIdx.x;
    const int lane = tid & 63;
    const int wv  = tid >> 6;          // 0..7
    const int lo  = lane & 15;
    const int hi  = lane >> 4;         // 0..3

    const float* table = dir ? tableB : tableF;
    const float* Whh   = dir ? WhhB : WhhF;
    float* emOut       = dir ? emB : emF;

    __shared__ __align__(16) unsigned short h_lds[2][16][264];  // [buf][b][col], 16.9 KiB

    const int colg = jb * 128 + wv * 16 + lo;     // this lane's h-col (0..255)
    const int bb0 = g * GB;
    const int pbase = (jb ^ 1) * 2048;            // partner half, in u32 words
    const int pcol  = (jb ^ 1) * 128 + (tid >> 2);
    const int pb0   = (tid & 3) * 4;

    // ---- preload Whh B-fragments: B[k][col] = Whh[q*HH+colg][k] ----
    short8 wfrag[4][8];
#pragma unroll
    for (int q = 0; q < 4; ++q) {
        const float* wrow = Whh + (size_t)(q * HH + colg) * HH;
#pragma unroll
        for (int kb = 0; kb < 8; ++kb) {
            const float4* p4 = (const float4*)(wrow + kb * 32 + hi * 8);
            float4 a = p4[0], b = p4[1];
            short8 f;
            f[0] = (short)f2b(a.x); f[1] = (short)f2b(a.y);
            f[2] = (short)f2b(a.z); f[3] = (short)f2b(a.w);
            f[4] = (short)f2b(b.x); f[5] = (short)f2b(b.y);
            f[6] = (short)f2b(b.z); f[7] = (short)f2b(b.w);
            wfrag[q][kb] = f;
        }
    }
    // ---- em B-fragments (fcW), used by block jb==0 wave 0 only ----
    short8 efrag[8];
    if (jb == 0 && wv == 0) {
#pragma unroll
        for (int kb = 0; kb < 8; ++kb) {
            short8 f;
            if (lo < KK) {
                const float4* p4 = (const float4*)(fcW + lo * (2 * HH) + dir * HH + kb * 32 + hi * 8);
                float4 a = p4[0], b = p4[1];
                f[0] = (short)f2b(a.x); f[1] = (short)f2b(a.y);
                f[2] = (short)f2b(a.z); f[3] = (short)f2b(a.w);
                f[4] = (short)f2b(b.x); f[5] = (short)f2b(b.y);
                f[6] = (short)f2b(b.z); f[7] = (short)f2b(b.w);
            } else {
                for (int j = 0; j < 8; ++j) f[j] = 0;
            }
            efrag[kb] = f;
        }
    }

    float cst[4] = {0.f, 0.f, 0.f, 0.f};

    for (int s = 0; s <= TT; ++s) {
        // ---- (1) table gather issued first: hides L2 latency under the poll ----
        float tv[16];
        if (s < TT) {
            const int t = dir ? (TT - 1 - s) : s;
            int cid[4];
#pragma unroll
            for (int r = 0; r < 4; ++r) cid[r] = cidsT[t * BB + bb0 + hi * 4 + r];
#pragma unroll
            for (int q = 0; q < 4; ++q)
#pragma unroll
                for (int r = 0; r < 4; ++r)
                    tv[q * 4 + r] = table[(size_t)cid[r] * 1024 + q * HH + colg];
        }

        // ---- (2) poll partner half of h_{s-1} (slot (s+1)&1, tag s), ping-pong 2-deep ----
        if (s > 0) {
            const unsigned* psrc = hws + (size_t)(((s + 1) & 1) * 32 + gi) * 4096 + pbase + tid * 4;
            const unsigned want = ((unsigned)s) << 16;
            uint4v wa, wb, wres;
            asm volatile("global_load_dwordx4 %0, %1, off sc0 sc1" : "=v"(wa) : "v"(psrc) : "memory");
            asm volatile("global_load_dwordx4 %0, %1, off sc0 sc1" : "=v"(wb) : "v"(psrc) : "memory");
            for (;;) {
                asm volatile("s_waitcnt vmcnt(1)" ::: "memory");   // oldest (wa) complete
                if (((wa[0] & 0xffff0000u) == want) & ((wa[1] & 0xffff0000u) == want) &
                    ((wa[2] & 0xffff0000u) == want) & ((wa[3] & 0xffff0000u) == want)) { wres = wa; break; }
                asm volatile("global_load_dwordx4 %0, %1, off sc0 sc1" : "=v"(wa) : "v"(psrc) : "memory");
                asm volatile("s_waitcnt vmcnt(1)" ::: "memory");   // wb complete
                if (((wb[0] & 0xffff0000u) == want) & ((wb[1] & 0xffff0000u) == want) &
                    ((wb[2] & 0xffff0000u) == want) & ((wb[3] & 0xffff0000u) == want)) { wres = wb; break; }
                asm volatile("global_load_dwordx4 %0, %1, off sc0 sc1" : "=v"(wb) : "v"(psrc) : "memory");
            }
            asm volatile("s_waitcnt vmcnt(0)" ::: "memory");       // drain the in-flight extra load
            unsigned short (*hl)[264] = h_lds[s & 1];
            hl[pb0 + 0][pcol] = (unsigned short)wres[0];
            hl[pb0 + 1][pcol] = (unsigned short)wres[1];
            hl[pb0 + 2][pcol] = (unsigned short)wres[2];
            hl[pb0 + 3][pcol] = (unsigned short)wres[3];
        }
        __syncthreads();

        // ---- (3) gates MFMA + nonlinearity + tagged h store + own-half LDS write ----
        if (s < TT) {
            floatx4 acc[4];
#pragma unroll
            for (int q = 0; q < 4; ++q) {
                acc[q][0] = tv[q * 4 + 0]; acc[q][1] = tv[q * 4 + 1];
                acc[q][2] = tv[q * 4 + 2]; acc[q][3] = tv[q * 4 + 3];
            }
            if (s > 0) {
                const unsigned short (*hl)[264] = h_lds[s & 1];
#pragma unroll
                for (int kb = 0; kb < 8; ++kb) {
                    short8 a = *(const short8*)&hl[lo][kb * 32 + hi * 8];
#pragma unroll
                    for (int q = 0; q < 4; ++q)
                        acc[q] = __builtin_amdgcn_mfma_f32_16x16x32_bf16(a, wfrag[q][kb], acc[q], 0, 0, 0);
                }
            }
            unsigned hb[4];
            float hv[4];
#pragma unroll
            for (int r = 0; r < 4; ++r) {
                float iv = acc[0][r], fv = acc[1][r], gv = acc[2][r], ov = acc[3][r];
                float cn = fsig(fv) * cst[r] + fsig(iv) * ftanh(gv);
                cst[r] = cn;
                hv[r] = fsig(ov) * ftanh(cn);
                hb[r] = (unsigned)f2b(hv[r]);
            }
            const unsigned tagw = ((unsigned)(s + 1)) << 16;
            uint4v pv;
            pv[0] = tagw | hb[0]; pv[1] = tagw | hb[1];
            pv[2] = tagw | hb[2]; pv[3] = tagw | hb[3];
            unsigned* dst = hws + (size_t)((s & 1) * 32 + gi) * 4096 + colg * 16 + hi * 4;
            asm volatile("global_store_dwordx4 %0, %1, off sc0 sc1"
                         :: "v"(dst), "v"(pv) : "memory");
            // own half straight to next step's LDS buffer
            unsigned short (*hw)[264] = h_lds[(s + 1) & 1];
            hw[hi * 4 + 0][colg] = (unsigned short)hb[0];
            hw[hi * 4 + 1][colg] = (unsigned short)hb[1];
            hw[hi * 4 + 2][colg] = (unsigned short)hb[2];
            hw[hi * 4 + 3][colg] = (unsigned short)hb[3];
        }

        // ---- (4) em for h_{s-1} — after the h store, off the critical path ----
        if (s > 0 && jb == 0 && wv == 0) {
            const unsigned short (*hl)[264] = h_lds[s & 1];
            floatx4 eacc = {0.f, 0.f, 0.f, 0.f};
#pragma unroll
            for (int kb = 0; kb < 8; ++kb) {
                short8 a = *(const short8*)&hl[lo][kb * 32 + hi * 8];
                eacc = __builtin_amdgcn_mfma_f32_16x16x32_bf16(a, efrag[kb], eacc, 0, 0, 0);
            }
            if (lo < KK) {
                const int te = dir ? (TT - s) : (s - 1);
                float* eo = emOut + (size_t)(te * BB + bb0) * KK + lo;
#pragma unroll
                for (int r = 0; r < 4; ++r)
                    eo[(hi * 4 + r) * KK] = eacc[r];
            }
        }
    }
}

// ---------------- CRF partition (den): 16-lane group per batch row ----------------
__global__ void crf_den(const float* __restrict__ emF, const float* __restrict__ emB,
                        const float* __restrict__ fcb, const float* __restrict__ start_t,
                        const float* __restrict__ end_t, const float* __restrict__ trans,
                        float* __restrict__ den) {
    const int tid = threadIdx.x;
    const int j = tid & 15;
    const int grp = tid >> 4;               // 0..7
    const int b = blockIdx.x * 8 + grp;
    const bool valid = j < KK;

    __shared__ float expT[15][16];
    for (int idx = tid; idx < 240; idx += 128) {
        int i = idx >> 4, jj = idx & 15;
        expT[i][jj] = (jj < KK) ? __expf(trans[i * KK + jj]) : 0.f;
    }
    __syncthreads();

    float fcbj = valid ? fcb[j] : 0.f;
    float alpha = -1e30f;
    if (valid) alpha = start_t[j] + emF[b * KK + j] + emB[b * KK + j] + fcbj;

    for (int t = 1; t < TT; ++t) {
        float m = alpha;
#pragma unroll
        for (int off = 8; off; off >>= 1)
            m = fmaxf(m, __shfl_xor(m, off, 16));
        float e = __expf(alpha - m);
        float S = 0.f;
#pragma unroll
        for (int i = 0; i < KK; ++i)
            S += __shfl(e, i, 16) * expT[i][j];
        float emv = 0.f;
        if (valid) emv = emF[(t * BB + b) * KK + j] + emB[(t * BB + b) * KK + j] + fcbj;
        float na = m + __logf(S) + emv;
        alpha = valid ? na : -1e30f;
    }
    float v = valid ? (alpha + end_t[j]) : -1e30f;
    float m = v;
#pragma unroll
    for (int off = 8; off; off >>= 1) m = fmaxf(m, __shfl_xor(m, off, 16));
    float e = __expf(v - m);
#pragma unroll
    for (int off = 8; off; off >>= 1) e += __shfl_xor(e, off, 16);
    if (j == 0) den[b] = m + __logf(e);
}

// ---------------- CRF numerator partials over t-chunks ----------------
__global__ void crf_num_part(const float* __restrict__ emF, const float* __restrict__ emB,
                             const float* __restrict__ fcb, const float* __restrict__ start_t,
                             const float* __restrict__ trans, const int* __restrict__ labelsT,
                             float* __restrict__ part) {
    const int b = threadIdx.x;
    const int q = blockIdx.x;
    const int t0 = q * 64;
    float p = 0.f;
    int lp = (t0 > 0) ? labelsT[(t0 - 1) * BB + b] : 0;
    for (int t = t0; t < t0 + 64; ++t) {
        int l = labelsT[t * BB + b];
        float em = emF[(t * BB + b) * KK + l] + emB[(t * BB + b) * KK + l] + fcb[l];
        if (t == 0) p += start_t[l] + em;
        else        p += trans[lp * KK + l] + em;
        lp = l;
    }
    part[q * BB + b] = p;
}

// ---------------- finalize ----------------
__global__ void finalize(const float* __restrict__ part, const float* __restrict__ den,
                         const float* __restrict__ end_t, const int* __restrict__ labelsT,
                         float* __restrict__ out) {
    const int b = threadIdx.x;
    float num = 0.f;
#pragma unroll
    for (int q = 0; q < 8; ++q) num += part[q * BB + b];
    num += end_t[labelsT[(TT - 1) * BB + b]];
    float v = num - den[b];
    __shared__ float red[256];
    red[b] = v;
    __syncthreads();
    for (int st = 128; st; st >>= 1) {
        if (b < st) red[b] += red[b + st];
        __syncthreads();
    }
    if (b == 0) out[0] = -(red[0] / (float)BB);
}

extern "C" void kernel_launch(void* const* d_in, const int* in_sizes, int n_in,
                              void* d_out, int out_size, void* d_ws, size_t ws_size,
                              hipStream_t stream) {
    const int* char_ids   = (const int*)d_in[0];
    const int* labels     = (const int*)d_in[1];
    const float* embed    = (const float*)d_in[3];
    const float* WihF     = (const float*)d_in[4];
    const float* WhhF     = (const float*)d_in[5];
    const float* bF       = (const float*)d_in[6];
    const float* WihB     = (const float*)d_in[7];
    const float* WhhB     = (const float*)d_in[8];
    const float* bB       = (const float*)d_in[9];
    const float* fcW      = (const float*)d_in[10];
    const float* fcb      = (const float*)d_in[11];
    const float* start_t  = (const float*)d_in[12];
    const float* end_t    = (const float*)d_in[13];
    const float* trans    = (const float*)d_in[14];

    char* w = (char*)d_ws;
    float* tableF = (float*)w;          w += 128 * 1024 * 4;
    float* tableB = (float*)w;          w += 128 * 1024 * 4;
    int* cidsT    = (int*)w;            w += 512 * 256 * 4;
    int* labelsT  = (int*)w;            w += 512 * 256 * 4;
    unsigned* hws = (unsigned*)w;       w += 2 * 32 * 4096 * 4;       // 1 MiB (parity-doubled)
    float* emF    = (float*)w;          w += 512 * 256 * 15 * 4;
    float* emB    = (float*)w;          w += 512 * 256 * 15 * 4;
    float* den    = (float*)w;          w += 256 * 4;
    float* part   = (float*)w;          w += 8 * 256 * 4;

    hipMemsetAsync(hws, 0, 2 * 32 * 4096 * 4, stream);
    prep_fused<<<2048, 256, 0, stream>>>(char_ids, labels, cidsT, labelsT,
                                         embed, WihF, bF, WihB, bB, tableF, tableB);

    void* args[] = { (void*)&tableF, (void*)&tableB, (void*)&WhhF, (void*)&WhhB,
                     (void*)&fcW, (void*)&cidsT, (void*)&hws, (void*)&emF, (void*)&emB };
    hipLaunchCooperativeKernel((void*)bilstm, dim3(64), dim3(512), args, 0, stream);

    crf_den<<<32, 128, 0, stream>>>(emF, emB, fcb, start_t, end_t, trans, den);
    crf_num_part<<<8, 256, 0, stream>>>(emF, emB, fcb, start_t, trans, labelsT, part);
    finalize<<<1, 256, 0, stream>>>(part, den, end_t, labelsT, (float*)d_out);
}